// Round 2
// baseline (1366.537 us; speedup 1.0000x reference)
//
#include <hip/hip_runtime.h>

#define N_DIM          64
#define N_IMAGES       1024
#define ROWS_PER_BLOCK 2048
#define THREADS        256
#define GROUP          8      // sampled rows per pipeline stage
#define STRIDE         16     // row stride between a thread's samples

typedef float v4f __attribute__((ext_vector_type(4)));
typedef int   v4i __attribute__((ext_vector_type(4)));

// Phase A: per-block contiguous chunk of 2048 rows.
//  - id copy (int4 -> float4, nontemporal stores)
//  - segment sums, software-pipelined one GROUP (8 sampled rows, 8KB/wave)
//    ahead. All loads unconditional (plain, not nt — match the m13 6.3TB/s
//    config). Sorted ids => single guard compare on the group's LAST id
//    covers all 8 samples (cur <= id[k] <= id[last] == cur => all == cur).
//  - accumulates directly into d_out (out_avg/out_counts); NO workspace use.
__global__ __launch_bounds__(THREADS) void ImageAverage_phaseA(
    const float* __restrict__ x,
    const int*   __restrict__ ids,
    float*       __restrict__ out_avg,     // [N_IMAGES*N_DIM] fp32, pre-zeroed
    float*       __restrict__ out_counts,  // [N_IMAGES] fp32, pre-zeroed
    float*       __restrict__ out_id)      // [n_reflns] float copy of ids
{
    const int t = threadIdx.x;
    const long long blockRow0 = (long long)blockIdx.x * ROWS_PER_BLOCK;

    // ---- id copy: fully coalesced, nontemporal stores ----
    {
        const v4i* idv  = (const v4i*)(ids + blockRow0);
        v4f*       outv = (v4f*)(out_id + blockRow0);
        #pragma unroll
        for (int k = 0; k < ROWS_PER_BLOCK / 4 / THREADS; ++k) {   // 2
            v4i v = idv[k * THREADS + t];
            v4f f;
            f.x = (float)v.x; f.y = (float)v.y; f.z = (float)v.z; f.w = (float)v.w;
            __builtin_nontemporal_store(f, &outv[k * THREADS + t]);
        }
    }

    // ---- segment sums ----
    // thread -> 4 consecutive dims (float4), rows strided by 16
    const int dimGroup = t & 15;        // 0..15
    const int d0       = dimGroup * 4;  // starting dim
    const int rowOff   = t >> 4;        // 0..15
    const bool isCounter = (dimGroup == 0);

    v4f  sum = {0.f, 0.f, 0.f, 0.f};
    float cnt = 0.f;

    long long row = blockRow0 + rowOff;
    int cur = ids[row];

    v4f va[GROUP], vb[GROUP];   // constant-indexed only (fully unrolled)
    int idA, idB;

    // consume one group whose 8 values are already in registers
    auto consume = [&](const v4f (&v)[GROUP], int idLast, long long grow) {
        if (idLast == cur) {
            // fast path: all 8 sampled rows belong to cur
            sum += ((v[0] + v[1]) + (v[2] + v[3])) + ((v[4] + v[5]) + (v[6] + v[7]));
            cnt += (float)GROUP;
        } else {
            // slow path: boundary inside the group (rare). Values already in
            // registers; only the 7 interior ids need (L2-hot) loads.
            #pragma unroll
            for (int k = 0; k < GROUP; ++k) {
                const int id = (k < GROUP - 1) ? ids[grow + STRIDE * k] : idLast;
                if (id != cur) {
                    float* ap = out_avg + (long long)cur * N_DIM + d0;
                    atomicAdd(ap + 0, sum.x);
                    atomicAdd(ap + 1, sum.y);
                    atomicAdd(ap + 2, sum.z);
                    atomicAdd(ap + 3, sum.w);
                    if (isCounter) atomicAdd(&out_counts[cur], cnt);
                    sum = (v4f){0.f, 0.f, 0.f, 0.f};
                    cnt = 0.f;
                    cur = id;
                }
                sum += v[k];
                cnt += 1.f;
            }
        }
    };

    const int NGROUPS = ROWS_PER_BLOCK / STRIDE / GROUP;   // 16

    // prologue: group 0 loads
    #pragma unroll
    for (int k = 0; k < GROUP; ++k)
        va[k] = *(const v4f*)(x + (row + STRIDE * k) * N_DIM + d0);
    idA = ids[row + STRIDE * (GROUP - 1)];

    for (int g = 0; g < NGROUPS - 1; ++g) {
        const long long rowN = row + STRIDE * GROUP;
        // prefetch group g+1 (always in-bounds within the block: no guard)
        #pragma unroll
        for (int k = 0; k < GROUP; ++k)
            vb[k] = *(const v4f*)(x + (rowN + STRIDE * k) * N_DIM + d0);
        idB = ids[rowN + STRIDE * (GROUP - 1)];

        consume(va, idA, row);

        #pragma unroll
        for (int k = 0; k < GROUP; ++k) va[k] = vb[k];
        idA = idB;
        row = rowN;
    }
    consume(va, idA, row);   // epilogue: last group

    // final flush
    {
        float* ap = out_avg + (long long)cur * N_DIM + d0;
        atomicAdd(ap + 0, sum.x);
        atomicAdd(ap + 1, sum.y);
        atomicAdd(ap + 2, sum.z);
        atomicAdd(ap + 3, sum.w);
        if (isCounter) atomicAdd(&out_counts[cur], cnt);
    }
}

// Phase B: in-place averaged = accum / max(count,1); counts already float.
__global__ __launch_bounds__(THREADS) void ImageAverage_phaseB(
    float*       __restrict__ out_avg,
    const float* __restrict__ out_counts)
{
    const int i = blockIdx.x * blockDim.x + threadIdx.x;
    if (i < N_IMAGES * N_DIM) {
        const float c = out_counts[i >> 6];
        const float denom = (c > 0.f) ? c : 1.f;
        out_avg[i] = out_avg[i] / denom;
    }
}

extern "C" void kernel_launch(void* const* d_in, const int* in_sizes, int n_in,
                              void* d_out, int out_size, void* d_ws, size_t ws_size,
                              hipStream_t stream) {
    const float* x   = (const float*)d_in[0];
    const int*   ids = (const int*)d_in[1];
    const int n_reflns = in_sizes[1];          // 4194304

    // output layout (all float32): [avg 1024*64][id copy n_reflns][counts 1024]
    float* out_avg    = (float*)d_out;
    float* out_id     = out_avg + (size_t)N_IMAGES * N_DIM;
    float* out_counts = out_id + (size_t)n_reflns;

    // accumulate directly into the output buffer: d_ws is UNUSED.
    hipMemsetAsync(out_avg,    0, (size_t)N_IMAGES * N_DIM * sizeof(float), stream);
    hipMemsetAsync(out_counts, 0, (size_t)N_IMAGES * sizeof(float), stream);

    const int gridA = n_reflns / ROWS_PER_BLOCK;   // 2048
    ImageAverage_phaseA<<<gridA, THREADS, 0, stream>>>(x, ids, out_avg, out_counts, out_id);

    const int nB = N_IMAGES * N_DIM;               // 65536
    ImageAverage_phaseB<<<(nB + THREADS - 1) / THREADS, THREADS, 0, stream>>>(
        out_avg, out_counts);
}